// Round 6
// baseline (167.345 us; speedup 1.0000x reference)
//
#include <hip/hip_runtime.h>

#define DD 160
#define HH 192
#define WW 160
#define HWs (HH * WW)          // 30720
#define NTOT 9830400.0f        // 2*160*192*160
#define DOUT 40                // output slices per block
#define NIT  48                // DOUT + 8 halo
#define NBLK 480

typedef float    v4 __attribute__((ext_vector_type(4)));
typedef float    v8 __attribute__((ext_vector_type(8)));
typedef _Float16 h4 __attribute__((ext_vector_type(4)));
typedef _Float16 h8 __attribute__((ext_vector_type(8)));

// CK-style workgroup barrier that waits ONLY on LDS (lgkmcnt(0)), leaving
// global prefetch loads in flight. __syncthreads() would emit
// s_waitcnt vmcnt(0) before s_barrier and drain the software pipeline
// (that drain was round-5's ~3500 cyc/iter stall).
__device__ __forceinline__ void block_sync_lds() {
    __builtin_amdgcn_s_waitcnt(0xc07f);   // vmcnt=63, expcnt=7, lgkmcnt=0
    __builtin_amdgcn_s_barrier();
}

// Fully-fused NCC, software-pipelined with depth-2 global prefetch:
// per block one 32(w)x16(h) tile x 40 output slices. Iteration t:
//   stage p0 (slice si, loaded at t-2) -> raw[t&1]; rotate p0<-p1;
//   issue load of slice si+2 -> p1; LDS-only barrier; then concurrently:
//   waves w/ rtid<160  : H pass raw[t&1] -> hsb[t&1] (9-tap, 5ch, fp16)
//   wave  w/ rtid>=192 : W pass hsb[(t-1)&1] -> fp16x8 ring -> rolling D-sums
//                        -> cc epilogue (8 outputs/thread)
// Race audit (one barrier/iter, parity double-buffer):
//   H(t) writes hsb[t&1]; last reader W(t-2) finished before bar(t). OK
//   stage(t) writes raw[t&1]; last reader H(t-2) finished before bar(t-1). OK
//   prefetch loads cross the barrier in-registers only -> no visibility need.
// fp16 ring: rolling add/sub uses identical rounded values -> cancels exactly;
// final mean err ~1e-5 << 5.8e-4 threshold.
__global__ __launch_bounds__(256, 2) void kf(const float* __restrict__ I,
                                             const float* __restrict__ J,
                                             float* __restrict__ partial) {
    __shared__ float rawb[2][2][24][40];   // [parity][input][row][col] 15360 B
    __shared__ h4    hsb[2][5][16][10];    // [parity][ch][row][f4col]  12800 B
    __shared__ h8    ring[9][5][64];       // [slot][ch][f8col]         46080 B

    const int tid = threadIdx.x;
    const int bx  = blockIdx.x;
    const int b   = blockIdx.z;
    const int tx  = bx % 5, ty = bx / 5;   // 5 w-tiles x 12 h-tiles
    const int w0 = tx * 32, h0 = ty * 16;
    const int d0 = blockIdx.y * DOUT;
    const int bid = bx + 60 * (blockIdx.y + 4 * b);

    // wave roles; W-wave lands on SIMD3 (even bx) or SIMD1 (odd bx).
    const int  rtid = tid ^ ((bx & 1) << 7);
    const bool isW  = (rtid >= 192);
    const bool isH  = (rtid < 160);
    const int  p    = rtid & 63;           // W lane: f8-output id
    const int  wr   = p >> 2, wg8 = p & 3; // row, f8-col-group
    const int  hr   = rtid / 10, hk = rtid % 10;   // H task (row, f4col)

    // ---- staging decode: 480 f4-tasks (0..239 I, 240..479 J), stride-40 rows
    const int  uA   = tid;
    const int  qA   = (uA < 240) ? uA : uA - 240;
    const int  inpA = (uA < 240) ? 0 : 1;
    const int  rowA = qA / 10, gA = qA % 10;
    const int  ghA = h0 - 4 + rowA, gwA = w0 - 4 + gA * 4;
    const bool okA = (ghA >= 0 && ghA < HH && gwA >= 0 && gwA < WW);
    const size_t offA = (size_t)ghA * WW + gwA;
    const int  ldsA = inpA * 960 + rowA * 40 + gA * 4;
    const float* srcA = inpA ? J : I;

    const bool hasB = (tid < 224);         // taskB = tid+256 in [256,480) -> J
    const int  qB   = tid + 16;
    const int  rowB = qB / 10, gB = qB % 10;
    const int  ghB = h0 - 4 + rowB, gwB = w0 - 4 + gB * 4;
    const bool okB = hasB && (ghB >= 0 && ghB < HH && gwB >= 0 && gwB < WW);
    const size_t offB = (size_t)ghB * WW + gwB;
    const int  ldsB = 960 + rowB * 40 + gB * 4;

    float* rawF = &rawb[0][0][0][0];
    const size_t base_b = (size_t)b * DD * HWs;

    // depth-2 prefetch registers: at entry of iter t,
    //   p0 = slice(d0-4+t), p1 = slice(d0-4+t+1)
    v4 p0A = (v4)0.f, p0B = (v4)0.f, p1A = (v4)0.f, p1B = (v4)0.f;
    {
        const int s0 = d0 - 4;
        if (s0 >= 0) {
            const size_t sb = base_b + (size_t)s0 * HWs;
            if (okA) p0A = *(const v4*)(srcA + sb + offA);
            if (okB) p0B = *(const v4*)(J + sb + offB);
        }
        const int s1 = d0 - 3;
        if (s1 >= 0) {
            const size_t sb = base_b + (size_t)s1 * HWs;
            if (okA) p1A = *(const v4*)(srcA + sb + offA);
            if (okB) p1B = *(const v4*)(J + sb + offB);
        }
    }

    v8 S[5] = {(v8)0.f, (v8)0.f, (v8)0.f, (v8)0.f, (v8)0.f};
    v8 accv = (v8)0.f;
    int wslot = 0;
    const float inv = 1.0f / 729.0f;

    for (int t = 0; t <= NIT; ++t) {
        const int  si  = d0 - 4 + t;
        const bool sv  = (t < NIT) && (si >= 0 && si < DD);  // block-uniform
        const int  par = t & 1;

        if (sv) {   // stage slice si (regs loaded at t-2) -> raw[par]
            *(v4*)(rawF + par * 1920 + ldsA) = p0A;
            if (hasB) *(v4*)(rawF + par * 1920 + ldsB) = p0B;
        }
        // rotate pipeline and issue prefetch of slice si+2 (consumed at t+2)
        p0A = p1A; p0B = p1B;
        {
            const int sn = si + 2;
            if (t + 2 < NIT && sn >= 0 && sn < DD) {
                const size_t sb = base_b + (size_t)sn * HWs;
                p1A = okA ? *(const v4*)(srcA + sb + offA) : (v4)0.f;
                if (hasB) p1B = okB ? *(const v4*)(J + sb + offB) : (v4)0.f;
            }
        }
        block_sync_lds();    // LDS-only barrier: vmem stays in flight

        if (sv && isH) {     // H pass: 9-tap vertical, 5 channels -> fp16
            v4 sI = (v4)0.f, sJ = (v4)0.f, sII = (v4)0.f, sJJ = (v4)0.f,
               sIJ = (v4)0.f;
#pragma unroll
            for (int tt = 0; tt < 9; ++tt) {
                v4 a  = *(const v4*)&rawb[par][0][hr + tt][hk * 4];
                v4 bb = *(const v4*)&rawb[par][1][hr + tt][hk * 4];
                sI += a; sJ += bb; sII += a * a; sJJ += bb * bb; sIJ += a * bb;
            }
            hsb[par][0][hr][hk] = __builtin_convertvector(sI,  h4);
            hsb[par][1][hr][hk] = __builtin_convertvector(sJ,  h4);
            hsb[par][2][hr][hk] = __builtin_convertvector(sII, h4);
            hsb[par][3][hr][hk] = __builtin_convertvector(sJJ, h4);
            hsb[par][4][hr][hk] = __builtin_convertvector(sIJ, h4);
        }

        if (t >= 1 && isW) { // W pass for slice t-1 + ring + rolling D + cc
            const int tp  = t - 1;
            const int sip = d0 - 4 + tp;
            v8 o[5];
            if (sip >= 0 && sip < DD) {
                const int pb = tp & 1;
#pragma unroll
                for (int c = 0; c < 5; ++c) {
                    const h4* hp = &hsb[pb][c][wr][wg8 * 2];
                    v8 fa = __builtin_convertvector(*(const h8*)hp, v8);
                    v8 fb = __builtin_convertvector(*(const h8*)(hp + 2), v8);
                    float s = fa[0] + fa[1] + fa[2] + fa[3] + fa[4] + fa[5] +
                              fa[6] + fa[7] + fb[0];
                    v8 ov; ov[0] = s;
                    s = s - fa[0] + fb[1]; ov[1] = s;
                    s = s - fa[1] + fb[2]; ov[2] = s;
                    s = s - fa[2] + fb[3]; ov[3] = s;
                    s = s - fa[3] + fb[4]; ov[4] = s;
                    s = s - fa[4] + fb[5]; ov[5] = s;
                    s = s - fa[5] + fb[6]; ov[6] = s;
                    s = s - fa[6] + fb[7]; ov[7] = s;
                    o[c] = ov;
                }
            } else {
#pragma unroll
                for (int c = 0; c < 5; ++c) o[c] = (v8)0.f;
            }
#pragma unroll
            for (int c = 0; c < 5; ++c) {
                h8 nv = __builtin_convertvector(o[c], h8);
                if (tp >= 9)
                    S[c] -= __builtin_convertvector(ring[wslot][c][p], v8);
                ring[wslot][c][p] = nv;
                S[c] += __builtin_convertvector(nv, v8);
            }
            if (++wslot == 9) wslot = 0;

            if (tp >= 8) {   // output depth d = d0 + tp - 8
                v8 mu1 = S[0] * inv, mu2 = S[1] * inv;
                v8 g1  = S[2] * inv - mu1 * mu1;
                v8 g2  = S[3] * inv - mu2 * mu2;
                v8 g12 = S[4] * inv - mu1 * mu2;
                v8 num = g12 * g12;
                v8 den = g1 * g2 + 1e-5f;
#pragma unroll
                for (int e = 0; e < 8; ++e)
                    accv[e] += __fdividef(num[e], den[e]);
            }
        }
    }

    // only the W wave holds acc: wave-local shuffle reduce, one store/block
    if (isW) {
        float a = accv[0] + accv[1] + accv[2] + accv[3] +
                  accv[4] + accv[5] + accv[6] + accv[7];
#pragma unroll
        for (int off = 32; off > 0; off >>= 1) a += __shfl_down(a, off);
        if (p == 0) partial[bid] = a;
    }
}

__global__ void k3_final(const float* __restrict__ partial,
                         float* __restrict__ out) {
    __shared__ float r[512];
    const int i = threadIdx.x;
    r[i] = (i < NBLK) ? partial[i] : 0.f;
    __syncthreads();
    for (int off = 256; off > 0; off >>= 1) {
        if (i < off) r[i] += r[i + off];
        __syncthreads();
    }
    if (i == 0) out[0] = -r[0] * (1.0f / NTOT);
}

extern "C" void kernel_launch(void* const* d_in, const int* in_sizes, int n_in,
                              void* d_out, int out_size, void* d_ws, size_t ws_size,
                              hipStream_t stream) {
    (void)in_sizes; (void)n_in; (void)out_size; (void)ws_size;
    const float* I = (const float*)d_in[0];   // y_true
    const float* J = (const float*)d_in[1];   // y_pred
    float* out     = (float*)d_out;
    float* partial = (float*)d_ws;            // NBLK floats, every slot written

    dim3 grid(60, 4, 2);                      // (5w x 12h tiles, D/40, B)
    kf<<<grid, 256, 0, stream>>>(I, J, partial);
    k3_final<<<1, 512, 0, stream>>>(partial, out);
}

// Round 7
// 153.275 us; speedup vs baseline: 1.0918x; 1.0918x over previous
//
#include <hip/hip_runtime.h>

#define DD 160
#define HH 192
#define WW 160
#define HWs (HH * WW)          // 30720
#define NTOT 9830400.0f        // 2*160*192*160
#define DOUT 20                // output slices per block
#define NIT  28                // DOUT + 8 halo
#define NBLK 960

#define SDS 11                 // SD row stride (h4 units; 10 used, +1 pad)
#define SDC (24 * SDS)         // 264: SD channel stride
#define HSS 11                 // HS row stride
#define HSC (16 * HSS)         // 176: HS channel stride

typedef float    v4 __attribute__((ext_vector_type(4)));
typedef _Float16 h4 __attribute__((ext_vector_type(4)));

// LDS-only barrier: leaves global prefetch loads in flight.
__device__ __forceinline__ void block_sync_lds() {
    __builtin_amdgcn_s_waitcnt(0xc07f);   // vmcnt=63, expcnt=7, lgkmcnt=0
    __builtin_amdgcn_s_barrier();
}
__device__ __forceinline__ v4 up(h4 x) { return __builtin_convertvector(x, v4); }
__device__ __forceinline__ h4 dn(v4 x) { return __builtin_convertvector(x, h4); }

// Fully-fused NCC, D-first separable order:
//  ph1 (tid<240): thread owns one w-float4 of the 40x24 halo region; rolling
//      9-window D-sums of {I,J,II,JJ,IJ} in registers. History = 9-deep
//      register FIFO of fp16-packed raw I/J (static index via 9x unroll);
//      products recomputed from the SAME fp16 values on add and subtract ->
//      exact cancellation. Writes 5 SD values (fp16) to LDS per iter.
//  ph2 (tid<100): 9-tap + sliding H-sum over SD -> HS (fp16, per (w4,ch,half))
//  ph3 (tid<128): sliding W-sum over HS + cc epilogue, 4 outputs/thread.
// Barriers: 2 per iter (LDS-only). WAR audit: ph1(t+1) runs after bar2(t) >
// ph2(t) done reading SDL; ph2(t+1) after bar1(t+1) > ph3(t) done reading
// HSL -> single-buffered LDS is safe. LDS = 18.1 KB -> 4 blocks/CU.
__global__ __launch_bounds__(256, 4) void kf(const float* __restrict__ I,
                                             const float* __restrict__ J,
                                             float* __restrict__ partial) {
    __shared__ h4    SDL[5 * SDC];   // [ch][row 24][g 10(+1)]  10560 B
    __shared__ h4    HSL[5 * HSC];   // [ch][h 16][g 10(+1)]     7040 B
    __shared__ float red[128];

    const int tid = threadIdx.x;
    const int bx = blockIdx.x, by = blockIdx.y, b = blockIdx.z;
    const int w0 = (bx % 5) * 32, h0 = (bx / 5) * 16;
    const int d0 = by * DOUT;
    const int bid = bx + 60 * (by + 8 * b);

    // ---- phase-1 decode: 240 columns = 24 rows x 10 f4-cols
    const bool p1 = tid < 240;
    const int r = tid / 10, g = tid % 10;
    const int gh = h0 - 4 + r, gw = w0 - 4 + g * 4;   // gw 16B-aligned
    const bool colOK = p1 && gh >= 0 && gh < HH && gw >= 0 && gw < WW;
    const size_t colOff = (size_t)gh * WW + gw;
    const float* Ib = I + (size_t)b * DD * HWs + colOff;
    const float* Jb = J + (size_t)b * DD * HWs + colOff;
    h4* const sdw = &SDL[r * SDS + g];

    // ---- phase-2 decode: 100 tasks = 10 f4cols x 5 ch x 2 h-halves
    const bool p2 = tid < 100;
    const int g2 = tid % 10, q2 = tid / 10;
    const int ch2 = q2 >> 1, hh0 = (q2 & 1) * 8;
    const h4* const sdr = &SDL[ch2 * SDC + hh0 * SDS + g2];
    h4* const hsw = &HSL[ch2 * HSC + hh0 * HSS + g2];

    // ---- phase-3 decode: 128 tasks = 16 h-rows x 8 w-segments of 4 outputs
    const bool p3 = tid < 128;
    const int hh = tid >> 3, sg = tid & 7;
    const h4* const hsr = &HSL[hh * HSS + sg];

    v4 sd0 = 0.f, sd1 = 0.f, sd2 = 0.f, sd3 = 0.f, sd4 = 0.f;
    h4 fI[9], fJ[9];
#pragma unroll
    for (int u = 0; u < 9; ++u) { fI[u] = (h4)(_Float16)0; fJ[u] = (h4)(_Float16)0; }
    v4 pLI = 0.f, pLJ = 0.f;
    float acc = 0.f;
    const float inv = 1.0f / 729.0f;

    {   // preload lead slice for t=0 (si=d0-4; <0 only for the d0=0 chunk)
        const int si = d0 - 4;
        if (colOK && si >= 0) {
            pLI = *(const v4*)(Ib + (size_t)si * HWs);
            pLJ = *(const v4*)(Jb + (size_t)si * HWs);
        }
    }

    for (int tb = 0; tb < NIT; tb += 9) {
#pragma unroll
        for (int u = 0; u < 9; ++u) {
            const int t = tb + u;
            if (t < NIT) {               // block-uniform guard
                const int si = d0 - 4 + t;
                if (p1) {
                    // round-trip through fp16 so add == later subtract
                    h4 cI = dn(pLI), cJ = dn(pLJ);
                    v4 aI = up(cI), aJ = up(cJ);
                    v4 dI = aI, dJv = aJ;
                    v4 dII = aI * aI, dJJ = aJ * aJ, dIJ = aI * aJ;
                    if (t >= 9) {        // retire slice si-9 (fifo slot u)
                        v4 bI = up(fI[u]), bJ = up(fJ[u]);
                        dI -= bI; dJv -= bJ;
                        dII -= bI * bI; dJJ -= bJ * bJ; dIJ -= bI * bJ;
                    }
                    fI[u] = cI; fJ[u] = cJ;
                    sd0 += dI; sd1 += dJv; sd2 += dII; sd3 += dJJ; sd4 += dIJ;
                    sdw[0]       = dn(sd0);
                    sdw[SDC]     = dn(sd1);
                    sdw[2 * SDC] = dn(sd2);
                    sdw[3 * SDC] = dn(sd3);
                    sdw[4 * SDC] = dn(sd4);
                    // prefetch lead slice for t+1 (in flight across barriers)
                    pLI = 0.f; pLJ = 0.f;
                    const int sn = si + 1;
                    if (t + 1 < NIT && colOK && sn >= 0 && sn < DD) {
                        pLI = *(const v4*)(Ib + (size_t)sn * HWs);
                        pLJ = *(const v4*)(Jb + (size_t)sn * HWs);
                    }
                }
                block_sync_lds();
                if (p2) {   // H: 9-tap then slide over 8 rows of this half
                    v4 s = 0.f;
#pragma unroll
                    for (int k = 0; k < 9; ++k) s += up(sdr[k * SDS]);
                    hsw[0] = dn(s);
#pragma unroll
                    for (int j2 = 1; j2 < 8; ++j2) {
                        s += up(sdr[(j2 + 8) * SDS]) - up(sdr[(j2 - 1) * SDS]);
                        hsw[j2 * HSS] = dn(s);
                    }
                }
                block_sync_lds();
                if (p3 && t >= 8) {   // W slide + cc, output depth d0+t-8
                    float w[5][4];
#pragma unroll
                    for (int c = 0; c < 5; ++c) {
                        v4 fa = up(hsr[c * HSC]);
                        v4 fb = up(hsr[c * HSC + 1]);
                        v4 fc = up(hsr[c * HSC + 2]);
                        float s = fa[0] + fa[1] + fa[2] + fa[3] +
                                  fb[0] + fb[1] + fb[2] + fb[3] + fc[0];
                        w[c][0] = s;
                        s += fc[1] - fa[0]; w[c][1] = s;
                        s += fc[2] - fa[1]; w[c][2] = s;
                        s += fc[3] - fa[2]; w[c][3] = s;
                    }
#pragma unroll
                    for (int e = 0; e < 4; ++e) {
                        float mu1 = w[0][e] * inv, mu2 = w[1][e] * inv;
                        float g1  = fmaf(-mu1, mu1, w[2][e] * inv);
                        float g2v = fmaf(-mu2, mu2, w[3][e] * inv);
                        float g12 = fmaf(-mu1, mu2, w[4][e] * inv);
                        acc += __fdividef(g12 * g12, fmaf(g1, g2v, 1e-5f));
                    }
                }
            }
        }
    }

    if (p3) red[tid] = acc;
    __syncthreads();
    if (tid < 64) {
        float a = red[tid] + red[tid + 64];
#pragma unroll
        for (int off = 32; off > 0; off >>= 1) a += __shfl_down(a, off);
        if (tid == 0) partial[bid] = a;
    }
}

__global__ void k3_final(const float* __restrict__ partial,
                         float* __restrict__ out) {
    __shared__ float r[1024];
    const int i = threadIdx.x;
    r[i] = (i < NBLK) ? partial[i] : 0.f;
    __syncthreads();
    for (int off = 512; off > 0; off >>= 1) {
        if (i < off) r[i] += r[i + off];
        __syncthreads();
    }
    if (i == 0) out[0] = -r[0] * (1.0f / NTOT);
}

extern "C" void kernel_launch(void* const* d_in, const int* in_sizes, int n_in,
                              void* d_out, int out_size, void* d_ws, size_t ws_size,
                              hipStream_t stream) {
    (void)in_sizes; (void)n_in; (void)out_size; (void)ws_size;
    const float* I = (const float*)d_in[0];   // y_true
    const float* J = (const float*)d_in[1];   // y_pred
    float* out     = (float*)d_out;
    float* partial = (float*)d_ws;            // NBLK floats, all written

    dim3 grid(60, 8, 2);                      // (5w x 12h tiles, D/20, B)
    kf<<<grid, 256, 0, stream>>>(I, J, partial);
    k3_final<<<1, 1024, 0, stream>>>(partial, out);
}

// Round 8
// 151.174 us; speedup vs baseline: 1.1070x; 1.0139x over previous
//
#include <hip/hip_runtime.h>

#define DD 160
#define HH 192
#define WW 160
#define HWs (HH * WW)          // 30720
#define NTOT 9830400.0f        // 2*160*192*160
#define DOUT 20                // output slices per block
#define NIT  28                // DOUT + 8 halo
#define NBLK 960

#define SDS 11                 // SD row stride (h4 units)
#define SDC (24 * SDS + 4)     // 268 h4 = 536 dw = 24 mod 32 (de-aliased)
#define HSR 44                 // HS row stride (floats); 44 dw, 16B-aligned
#define HSC (16 * HSR + 4)     // 708 floats = 4 mod 32 per channel

typedef float    v4 __attribute__((ext_vector_type(4)));
typedef _Float16 h4 __attribute__((ext_vector_type(4)));

// LDS-only barrier: leaves global prefetch loads in flight.
__device__ __forceinline__ void block_sync_lds() {
    __builtin_amdgcn_s_waitcnt(0xc07f);   // vmcnt=63, expcnt=7, lgkmcnt=0
    __builtin_amdgcn_s_barrier();
}
__device__ __forceinline__ v4 up(h4 x) { return __builtin_convertvector(x, v4); }
__device__ __forceinline__ h4 dn(v4 x) { return __builtin_convertvector(x, h4); }

// Fully-fused NCC, D-first separable order (round-7 structure), round-8:
//  - HS plane stored fp32 (bank-uniform strides) -> ph3 has ZERO fp16
//    converts, ph2 no down-converts (cvt tax was ~40% of round-7 VALU).
//  - ph2 rebalanced: 200 quarter-row tasks, 12 taps each (was 100 x 23 reads).
//  - SD channel stride padded to 268 h4: round-7 had ch-stride=16 (mod 32) ==
//    half-offset=16 -> systematic b64 bank aliasing (8.97e6 conflict cycles).
// Phases per iter t (2 LDS-only barriers):
//  ph1 (tid<240): rolling 9-window D-sums {I,J,II,JJ,IJ} in regs; 9-deep fp16
//      register FIFO of raw I/J; identical fp16 values on add & subtract ->
//      exact cancellation. Writes 5 fp16 SD values to LDS.
//  ph2 (tid<200): 9-tap + 3-slide H-sum over SD (fp32 acc) -> HS (fp32).
//  ph3 (tid<128): sliding W-sum over HS + cc epilogue, 4 outputs/thread.
// WAR audit (single-buffered, 2 barriers): ph1(t+1) writes SD after bar2(t) >=
// ph2(t) done reading; ph2(t+1) writes HS after bar1(t+1) >= ph3(t) done
// reading. LDS = 25.4 KB -> 4 blocks/CU.
__global__ __launch_bounds__(256, 4) void kf(const float* __restrict__ I,
                                             const float* __restrict__ J,
                                             float* __restrict__ partial) {
    __shared__ h4    SDL[5 * SDC];   // 10720 B
    __shared__ float HSL[5 * HSC];   // 14160 B
    __shared__ float red[128];

    const int tid = threadIdx.x;
    const int bx = blockIdx.x, by = blockIdx.y, b = blockIdx.z;
    const int w0 = (bx % 5) * 32, h0 = (bx / 5) * 16;
    const int d0 = by * DOUT;
    const int bid = bx + 60 * (by + 8 * b);

    // ---- phase-1 decode: 240 columns = 24 rows x 10 f4-cols
    const bool p1 = tid < 240;
    const int r = tid / 10, g = tid % 10;
    const int gh = h0 - 4 + r, gw = w0 - 4 + g * 4;   // gw 16B-aligned
    const bool colOK = p1 && gh >= 0 && gh < HH && gw >= 0 && gw < WW;
    const size_t colOff = (size_t)gh * WW + gw;
    const float* Ib = I + (size_t)b * DD * HWs + colOff;
    const float* Jb = J + (size_t)b * DD * HWs + colOff;
    h4* const sdw = &SDL[r * SDS + g];

    // ---- phase-2 decode: 200 tasks = 10 f4cols x 5 ch x 4 h-quarters
    const bool p2 = tid < 200;
    const int g2 = tid % 10, q2 = tid / 10;
    const int ch2 = q2 >> 2, qr = q2 & 3;             // quarter = 4 rows
    const h4*  const sdr = &SDL[ch2 * SDC + (qr * 4) * SDS + g2];
    float* const hsw = &HSL[ch2 * HSC + (qr * 4) * HSR + g2 * 4];

    // ---- phase-3 decode: 128 tasks = 16 h-rows x 8 w-segments of 4 outputs
    const bool p3 = tid < 128;
    const int hh = tid >> 3, sg = tid & 7;
    const float* const hsr = &HSL[hh * HSR + sg * 4];

    v4 sd0 = 0.f, sd1 = 0.f, sd2 = 0.f, sd3 = 0.f, sd4 = 0.f;
    h4 fI[9], fJ[9];
#pragma unroll
    for (int u = 0; u < 9; ++u) { fI[u] = (h4)(_Float16)0; fJ[u] = (h4)(_Float16)0; }
    v4 pLI = 0.f, pLJ = 0.f;
    float acc = 0.f;
    const float inv = 1.0f / 729.0f;

    {   // preload lead slice for t=0 (si=d0-4; <0 only for the d0=0 chunk)
        const int si = d0 - 4;
        if (colOK && si >= 0) {
            pLI = *(const v4*)(Ib + (size_t)si * HWs);
            pLJ = *(const v4*)(Jb + (size_t)si * HWs);
        }
    }

    for (int tb = 0; tb < NIT; tb += 9) {
#pragma unroll
        for (int u = 0; u < 9; ++u) {
            const int t = tb + u;
            if (t < NIT) {               // block-uniform guard
                const int si = d0 - 4 + t;
                if (p1) {
                    // round-trip through fp16 so add == later subtract
                    h4 cI = dn(pLI), cJ = dn(pLJ);
                    v4 aI = up(cI), aJ = up(cJ);
                    v4 dI = aI, dJv = aJ;
                    v4 dII = aI * aI, dJJ = aJ * aJ, dIJ = aI * aJ;
                    if (t >= 9) {        // retire slice si-9 (fifo slot u)
                        v4 bI = up(fI[u]), bJ = up(fJ[u]);
                        dI -= bI; dJv -= bJ;
                        dII -= bI * bI; dJJ -= bJ * bJ; dIJ -= bI * bJ;
                    }
                    fI[u] = cI; fJ[u] = cJ;
                    sd0 += dI; sd1 += dJv; sd2 += dII; sd3 += dJJ; sd4 += dIJ;
                    sdw[0]       = dn(sd0);
                    sdw[SDC]     = dn(sd1);
                    sdw[2 * SDC] = dn(sd2);
                    sdw[3 * SDC] = dn(sd3);
                    sdw[4 * SDC] = dn(sd4);
                    // prefetch lead slice for t+1 (in flight across barriers)
                    pLI = 0.f; pLJ = 0.f;
                    const int sn = si + 1;
                    if (t + 1 < NIT && colOK && sn >= 0 && sn < DD) {
                        pLI = *(const v4*)(Ib + (size_t)sn * HWs);
                        pLJ = *(const v4*)(Jb + (size_t)sn * HWs);
                    }
                }
                block_sync_lds();
                if (p2) {   // H: 9-tap then slide over this 4-row quarter
                    v4 s = 0.f;
#pragma unroll
                    for (int k = 0; k < 9; ++k) s += up(sdr[k * SDS]);
                    *(v4*)&hsw[0] = s;
#pragma unroll
                    for (int j2 = 1; j2 < 4; ++j2) {
                        s += up(sdr[(j2 + 8) * SDS]) - up(sdr[(j2 - 1) * SDS]);
                        *(v4*)&hsw[j2 * HSR] = s;
                    }
                }
                block_sync_lds();
                if (p3 && t >= 8) {   // W slide + cc, output depth d0+t-8
                    float w[5][4];
#pragma unroll
                    for (int c = 0; c < 5; ++c) {
                        const float* hp = hsr + c * HSC;
                        v4 fa = *(const v4*)hp;
                        v4 fb = *(const v4*)(hp + 4);
                        v4 fc = *(const v4*)(hp + 8);
                        float s = fa[0] + fa[1] + fa[2] + fa[3] +
                                  fb[0] + fb[1] + fb[2] + fb[3] + fc[0];
                        w[c][0] = s;
                        s += fc[1] - fa[0]; w[c][1] = s;
                        s += fc[2] - fa[1]; w[c][2] = s;
                        s += fc[3] - fa[2]; w[c][3] = s;
                    }
#pragma unroll
                    for (int e = 0; e < 4; ++e) {
                        float mu1 = w[0][e] * inv, mu2 = w[1][e] * inv;
                        float g1  = fmaf(-mu1, mu1, w[2][e] * inv);
                        float g2v = fmaf(-mu2, mu2, w[3][e] * inv);
                        float g12 = fmaf(-mu1, mu2, w[4][e] * inv);
                        acc += __fdividef(g12 * g12, fmaf(g1, g2v, 1e-5f));
                    }
                }
            }
        }
    }

    if (p3) red[tid] = acc;
    __syncthreads();
    if (tid < 64) {
        float a = red[tid] + red[tid + 64];
#pragma unroll
        for (int off = 32; off > 0; off >>= 1) a += __shfl_down(a, off);
        if (tid == 0) partial[bid] = a;
    }
}

__global__ void k3_final(const float* __restrict__ partial,
                         float* __restrict__ out) {
    __shared__ float r[1024];
    const int i = threadIdx.x;
    r[i] = (i < NBLK) ? partial[i] : 0.f;
    __syncthreads();
    for (int off = 512; off > 0; off >>= 1) {
        if (i < off) r[i] += r[i + off];
        __syncthreads();
    }
    if (i == 0) out[0] = -r[0] * (1.0f / NTOT);
}

extern "C" void kernel_launch(void* const* d_in, const int* in_sizes, int n_in,
                              void* d_out, int out_size, void* d_ws, size_t ws_size,
                              hipStream_t stream) {
    (void)in_sizes; (void)n_in; (void)out_size; (void)ws_size;
    const float* I = (const float*)d_in[0];   // y_true
    const float* J = (const float*)d_in[1];   // y_pred
    float* out     = (float*)d_out;
    float* partial = (float*)d_ws;            // NBLK floats, all written

    dim3 grid(60, 8, 2);                      // (5w x 12h tiles, D/20, B)
    kf<<<grid, 256, 0, stream>>>(I, J, partial);
    k3_final<<<1, 1024, 0, stream>>>(partial, out);
}

// Round 9
// 148.339 us; speedup vs baseline: 1.1281x; 1.0191x over previous
//
#include <hip/hip_runtime.h>

#define DD 160
#define HH 192
#define WW 160
#define HWs (HH * WW)          // 30720
#define NTOT 9830400.0f        // 2*160*192*160
#define DOUT 20                // output slices per block
#define NIT  28                // DOUT + 8 halo
#define NBLK 960

#define SDS 11                 // SD row stride (h4)
#define SDC (24 * SDS + 1)     // 265: SD channel stride
#define SDP (5 * SDC)          // 1325: SD plane (parity) stride
#define HSS 11                 // HS row stride (h4)
#define HSC (16 * HSS + 1)     // 177: HS channel stride
#define HSP (5 * HSC)          // 885: HS plane stride

typedef float    v4 __attribute__((ext_vector_type(4)));
typedef _Float16 h4 __attribute__((ext_vector_type(4)));

// LDS-only barrier: leaves global prefetch loads in flight.
__device__ __forceinline__ void block_sync_lds() {
    __builtin_amdgcn_s_waitcnt(0xc07f);   // vmcnt=63, expcnt=7, lgkmcnt=0
    __builtin_amdgcn_s_barrier();
}
__device__ __forceinline__ v4 up(h4 x) { return __builtin_convertvector(x, v4); }
__device__ __forceinline__ h4 dn(v4 x) { return __builtin_convertvector(x, h4); }

// Fully-fused NCC, D-first order, ONE barrier per iteration (depth-3 phase
// pipeline). Each iteration t, every thread runs up to three INDEPENDENT
// phase tasks back-to-back (intra-wave ILP hides LDS latency), then one
// LDS-only barrier:
//   ph1(t)   rt<240      : rolling 9-window D-sums {I,J,II,JJ,IJ}; 9-deep
//                          fp16 reg FIFO; writes 5 fp16 SD vals -> SD[t&1]
//   ph2(t-1) rt<100      : 9-tap + 8-row slide H-sum over SD[(t-1)&1],
//                          ALL packed-fp16 arithmetic -> HS[(t-1)&1]
//   ph3(t-2) rt>=128     : sliding W-sum over HS[t&1] + cc, 4 outputs/thread
// Parity audit: ph2(t)@iter t+1 reads SD[t&1] (bar-sep from ph1(t) write;
// next overwrite ph1(t+2)@t+2 after bar(t+1)). ph3(y)@iter y+2 reads HS[y&1]
// written @iter y+1 (bar-sep); overwritten by ph2(y+2)@iter y+3 after
// bar(y+2). All safe. Wave-role swap by block parity spreads the ph3-heavy
// waves across SIMDs. LDS 36.4 KB -> 4 blocks/CU.
__global__ __launch_bounds__(256, 4) void kf(const float* __restrict__ I,
                                             const float* __restrict__ J,
                                             float* __restrict__ partial) {
    __shared__ h4    SDL[2 * SDP];   // 21200 B
    __shared__ h4    HSL[2 * HSP];   // 14160 B
    __shared__ float red[256];       //  1024 B

    const int tid = threadIdx.x;
    const int bx = blockIdx.x, by = blockIdx.y, b = blockIdx.z;
    const int w0 = (bx % 5) * 32, h0 = (bx / 5) * 16;
    const int d0 = by * DOUT;
    const int bid = bx + 60 * (by + 8 * b);

    const int rt = tid ^ ((bx & 1) << 7);   // role swap waves 0,1 <-> 2,3

    // ---- ph1 decode: 240 columns = 24 rows x 10 f4-cols
    const bool p1 = rt < 240;
    const int r = rt / 10, g = rt % 10;
    const int gh = h0 - 4 + r, gw = w0 - 4 + g * 4;   // gw 16B-aligned
    const bool colOK = p1 && gh >= 0 && gh < HH && gw >= 0 && gw < WW;
    const size_t colOff = (size_t)gh * WW + gw;
    const float* Ib = I + (size_t)b * DD * HWs + colOff;
    const float* Jb = J + (size_t)b * DD * HWs + colOff;
    h4* const sdw = &SDL[r * SDS + g];

    // ---- ph2 decode: 100 tasks = 10 f4cols x 5 ch x 2 h-halves (8-row slide)
    const bool p2 = rt < 100;
    const int g2 = rt % 10, ch2 = (rt / 10) % 5, hh0 = (rt / 50) * 8;
    const int sdrOff = ch2 * SDC + hh0 * SDS + g2;
    const int hswOff = ch2 * HSC + hh0 * HSS + g2;

    // ---- ph3 decode: 128 tasks = 16 h-rows x 8 w-segments of 4 outputs
    const bool p3 = rt >= 128;
    const int q3 = rt & 127;
    const int hh = q3 >> 3, sg = q3 & 7;
    const int hsrOff = hh * HSS + sg;

    v4 sd0 = 0.f, sd1 = 0.f, sd2 = 0.f, sd3 = 0.f, sd4 = 0.f;
    h4 fI[9], fJ[9];
#pragma unroll
    for (int u = 0; u < 9; ++u) { fI[u] = (h4)(_Float16)0; fJ[u] = (h4)(_Float16)0; }
    v4 pLI = 0.f, pLJ = 0.f;
    float acc = 0.f;
    const float inv = 1.0f / 729.0f;

    {   // preload lead slice for t=0 (si = d0-4; <0 only for the d0=0 chunk)
        const int si = d0 - 4;
        if (colOK && si >= 0) {
            pLI = *(const v4*)(Ib + (size_t)si * HWs);
            pLJ = *(const v4*)(Jb + (size_t)si * HWs);
        }
    }

    for (int tb = 0; tb < 36; tb += 9) {
#pragma unroll
        for (int u = 0; u < 9; ++u) {
            const int t = tb + u;
            if (t < NIT + 2) {           // 30 iters; block-uniform guard
                // ---------- ph1(t): D-rolling, write SD[t&1]
                if (t < NIT && p1) {
                    h4 cI = dn(pLI), cJ = dn(pLJ);
                    v4 aI = up(cI), aJ = up(cJ);
                    v4 dI = aI, dJv = aJ;
                    v4 dII = aI * aI, dJJ = aJ * aJ, dIJ = aI * aJ;
                    if (t >= 9) {        // retire slice si-9 (fifo slot u)
                        v4 bI = up(fI[u]), bJ = up(fJ[u]);
                        dI -= bI; dJv -= bJ;
                        dII -= bI * bI; dJJ -= bJ * bJ; dIJ -= bI * bJ;
                    }
                    fI[u] = cI; fJ[u] = cJ;
                    sd0 += dI; sd1 += dJv; sd2 += dII; sd3 += dJJ; sd4 += dIJ;
                    h4* const sdq = sdw + (t & 1) * SDP;
                    sdq[0]       = dn(sd0);
                    sdq[SDC]     = dn(sd1);
                    sdq[2 * SDC] = dn(sd2);
                    sdq[3 * SDC] = dn(sd3);
                    sdq[4 * SDC] = dn(sd4);
                    // prefetch next lead slice (stays in flight across barrier)
                    pLI = 0.f; pLJ = 0.f;
                    const int sn = d0 - 3 + t;
                    if (t + 1 < NIT && colOK && sn >= 0 && sn < DD) {
                        pLI = *(const v4*)(Ib + (size_t)sn * HWs);
                        pLJ = *(const v4*)(Jb + (size_t)sn * HWs);
                    }
                }

                // ---------- ph2(t-1): H-sums in packed fp16, write HS
                if (t >= 1 && t <= NIT && p2) {
                    const int par = (t - 1) & 1;
                    const h4* const sdr = &SDL[par * SDP + sdrOff];
                    h4* const hsw = &HSL[par * HSP + hswOff];
                    h4 s = sdr[0];
#pragma unroll
                    for (int k = 1; k < 9; ++k) s += sdr[k * SDS];
                    hsw[0] = s;
#pragma unroll
                    for (int j = 1; j < 8; ++j) {
                        s += sdr[(j + 8) * SDS] - sdr[(j - 1) * SDS];
                        hsw[j * HSS] = s;
                    }
                }

                // ---------- ph3(t-2): W-slide + cc (output depth d0+t-10)
                if (t >= 10 && p3) {
                    const h4* const hsr = &HSL[(t & 1) * HSP + hsrOff];
                    float w[5][4];
#pragma unroll
                    for (int c = 0; c < 5; ++c) {
                        v4 fa = up(hsr[c * HSC]);
                        v4 fb = up(hsr[c * HSC + 1]);
                        v4 fc = up(hsr[c * HSC + 2]);
                        float s = fa[0] + fa[1] + fa[2] + fa[3] +
                                  fb[0] + fb[1] + fb[2] + fb[3] + fc[0];
                        w[c][0] = s;
                        s += fc[1] - fa[0]; w[c][1] = s;
                        s += fc[2] - fa[1]; w[c][2] = s;
                        s += fc[3] - fa[2]; w[c][3] = s;
                    }
#pragma unroll
                    for (int e = 0; e < 4; ++e) {
                        float mu1 = w[0][e] * inv, mu2 = w[1][e] * inv;
                        float g1  = fmaf(-mu1, mu1, w[2][e] * inv);
                        float g2v = fmaf(-mu2, mu2, w[3][e] * inv);
                        float g12 = fmaf(-mu1, mu2, w[4][e] * inv);
                        acc += __fdividef(g12 * g12, fmaf(g1, g2v, 1e-5f));
                    }
                }

                block_sync_lds();
            }
        }
    }

    red[tid] = acc;     // only p3 threads have nonzero acc
    __syncthreads();
    if (tid < 128) red[tid] += red[tid + 128];
    __syncthreads();
    if (tid < 64) {
        float a = red[tid] + red[tid + 64];
#pragma unroll
        for (int off = 32; off > 0; off >>= 1) a += __shfl_down(a, off);
        if (tid == 0) partial[bid] = a;
    }
}

__global__ void k3_final(const float* __restrict__ partial,
                         float* __restrict__ out) {
    __shared__ float r[1024];
    const int i = threadIdx.x;
    r[i] = (i < NBLK) ? partial[i] : 0.f;
    __syncthreads();
    for (int off = 512; off > 0; off >>= 1) {
        if (i < off) r[i] += r[i + off];
        __syncthreads();
    }
    if (i == 0) out[0] = -r[0] * (1.0f / NTOT);
}

extern "C" void kernel_launch(void* const* d_in, const int* in_sizes, int n_in,
                              void* d_out, int out_size, void* d_ws, size_t ws_size,
                              hipStream_t stream) {
    (void)in_sizes; (void)n_in; (void)out_size; (void)ws_size;
    const float* I = (const float*)d_in[0];   // y_true
    const float* J = (const float*)d_in[1];   // y_pred
    float* out     = (float*)d_out;
    float* partial = (float*)d_ws;            // NBLK floats, all written

    dim3 grid(60, 8, 2);                      // (5w x 12h tiles, D/20, B)
    kf<<<grid, 256, 0, stream>>>(I, J, partial);
    k3_final<<<1, 1024, 0, stream>>>(partial, out);
}